// Round 3
// baseline (12748.315 us; speedup 1.0000x reference)
//
#include <hip/hip_runtime.h>

// Problem constants
#define TT 256
#define BB 256
#define EE 512
#define HH 1024
#define G4 4096
#define KTOT 1536
#define NBLK 256

typedef __attribute__((ext_vector_type(8))) short short8;
typedef __attribute__((ext_vector_type(4))) float f32x4;

__device__ __forceinline__ short f2bf(float f) {
    unsigned u; __builtin_memcpy(&u, &f, 4);
    unsigned r = (u + 0x7FFFu + ((u >> 16) & 1u)) >> 16;   // RNE
    return (short)(unsigned short)r;
}
__device__ __forceinline__ float bf2f(short s) {
    unsigned u = ((unsigned)(unsigned short)s) << 16;
    float f; __builtin_memcpy(&f, &u, 4);
    return f;
}
__device__ __forceinline__ float sigf(float x) { return 1.f / (1.f + __expf(-x)); }

// ---------------------------------------------------------------------------
// Prep: w_cat[r][0:1024]=w_hh[r], w_cat[r][1024:1536]=w_ih[r] (bf16);
//       bias[r] = b_ih[r] + b_hh[r]
// ---------------------------------------------------------------------------
__global__ __launch_bounds__(256) void prep_kernel(
    const float* __restrict__ w_ih, const float* __restrict__ w_hh,
    const float* __restrict__ b_ih, const float* __restrict__ b_hh,
    short* __restrict__ w_cat, float* __restrict__ bias)
{
    int r = blockIdx.x;
    int tid = threadIdx.x;
    for (int c = tid; c < KTOT; c += 256) {
        float v = (c < HH) ? w_hh[(size_t)r * HH + c]
                           : w_ih[(size_t)r * EE + (c - HH)];
        w_cat[(size_t)r * KTOT + c] = f2bf(v);
    }
    if (tid == 0) bias[r] = b_ih[r] + b_hh[r];
}

// ---------------------------------------------------------------------------
// Gather + convert: x_bf[t][b][:] = bf16(emb[text[b][t]][:])
// ---------------------------------------------------------------------------
__global__ __launch_bounds__(256) void gather_kernel(
    const int* __restrict__ text, const float* __restrict__ emb,
    short* __restrict__ xbf)
{
    int row = blockIdx.x * 4 + (threadIdx.x >> 6);   // b*TT + t
    int b = row >> 8, t = row & 255;
    int lane = threadIdx.x & 63;
    int v = text[row];
    const float* src = emb + (size_t)v * EE + lane * 8;
    float4 f0 = *(const float4*)src;
    float4 f1 = *(const float4*)(src + 4);
    float fv[8];
    *(float4*)&fv[0] = f0; *(float4*)&fv[4] = f1;
    short8 s;
    #pragma unroll
    for (int i = 0; i < 8; ++i) s[i] = f2bf(fv[i]);
    *(short8*)(xbf + ((size_t)t * BB + b) * EE + lane * 8) = s;
}

// ---------------------------------------------------------------------------
// Persistent LSTM: all 256 steps in one launch.
// 256 blocks x 1024 threads (16 waves). LDS 149.5 KB forces 1 block/CU, so
// all 256 blocks are co-resident -> hand-rolled grid barrier is safe.
// Block tile: 64 batch x 16 j x 4 gates. Wave w: gate (w&3), b-subtile (w>>2).
// W_hh slice (64 rows x 1024 k, 128 KB) lives in LDS for the whole kernel.
// W_ih slice (64 KB) streams from L2 (XCD-pinned via swizzle). c in registers.
// ---------------------------------------------------------------------------
__global__ __launch_bounds__(1024, 4) void lstm_persist(
    const short* __restrict__ w_cat,   // [4096][1536] bf16
    const float* __restrict__ bias,    // [4096]
    const short* __restrict__ xbf,     // [T][B][E] bf16
    short* __restrict__ hbuf0,         // [B][H] bf16
    short* __restrict__ hbuf1,         // [B][H] bf16
    unsigned* __restrict__ bar)        // grid barrier counter (memset 0)
{
    __shared__ short Wl[64][1032];     // [g*16+n][k], +8 pad: 132096 B
    __shared__ float Gt[4][64][17];    // gate exchange: 17408 B

    const int tid  = threadIdx.x;
    const int wv   = tid >> 6;
    const int lane = tid & 63;
    const int g    = wv & 3;           // gate i,f,g,o
    const int mt   = wv >> 2;          // b-subtile 0..3
    const int n    = lane & 15;
    const int q    = lane >> 4;

    // XCD swizzle: blocks on XCD x share j-tiles {8x..8x+7}
    const int bid = blockIdx.x;
    const int xcd = bid & 7, sub = bid >> 3;
    const int j0  = (xcd * 8 + (sub & 7)) * 16;
    const int b0  = (sub >> 3) * 64;

    // Preload W_hh slice into LDS (once)
    for (int i = tid; i < 64 * 128; i += 1024) {
        int row = i >> 7, ch = i & 127;          // row = g*16+n, ch = 8-elem chunk
        int gg = row >> 4, nn = row & 15;
        *(short8*)&Wl[row][ch * 8] =
            *(const short8*)(w_cat + (size_t)(gg * HH + j0 + nn) * KTOT + ch * 8);
    }

    // Per-thread persistent epilogue state: element (em, en) of block patch
    const int em = tid >> 4;           // 0..63 (batch row in tile)
    const int en = tid & 15;           // 0..15 (j within tile)
    float creg = 0.f;
    const float b_i = bias[j0 + en];
    const float b_f = bias[HH + j0 + en];
    const float b_g = bias[2 * HH + j0 + en];
    const float b_o = bias[3 * HH + j0 + en];

    const short* wrow_x = w_cat + (size_t)(g * HH + j0 + n) * KTOT + HH; // x-part
    short* hO = hbuf0 + (size_t)(b0 + em) * HH + j0 + en;  // epilogue store addrs
    short* hE = hbuf1 + (size_t)(b0 + em) * HH + j0 + en;

    __syncthreads();   // Wl ready

    for (int t = 0; t < TT; ++t) {
        const short* hin = (t & 1) ? hbuf1 : hbuf0;

        f32x4 acc = (f32x4){0.f, 0.f, 0.f, 0.f};
        const short* arow_h = hin + (size_t)(b0 + mt * 16 + n) * HH + q * 8;
        const short* arow_x = xbf + ((size_t)t * BB + b0 + mt * 16 + n) * EE + q * 8;
        const short* Wrow   = &Wl[g * 16 + n][q * 8];

        if (t > 0) {   // h == 0 at t=0: skip the h-part chunks
            #pragma unroll 4
            for (int kc = 0; kc < 32; ++kc) {
                short8 af = *(const short8*)(arow_h + kc * 32);
                short8 bf = *(const short8*)(Wrow + kc * 32);
                acc = __builtin_amdgcn_mfma_f32_16x16x32_bf16(af, bf, acc, 0, 0, 0);
            }
        }
        #pragma unroll 4
        for (int kc = 0; kc < 16; ++kc) {
            short8 af = *(const short8*)(arow_x + kc * 32);
            short8 bf = *(const short8*)(wrow_x + q * 8 + kc * 32);
            acc = __builtin_amdgcn_mfma_f32_16x16x32_bf16(af, bf, acc, 0, 0, 0);
        }

        // Gate exchange (block-local)
        const int gm = mt * 16 + q * 4;
        Gt[g][gm + 0][n] = acc[0];
        Gt[g][gm + 1][n] = acc[1];
        Gt[g][gm + 2][n] = acc[2];
        Gt[g][gm + 3][n] = acc[3];
        __syncthreads();

        float ip = Gt[0][em][en] + b_i;
        float fp = Gt[1][em][en] + b_f;
        float gp = Gt[2][em][en] + b_g;
        float op = Gt[3][em][en] + b_o;
        float cn = sigf(fp) * creg + sigf(ip) * tanhf(gp);
        creg = cn;
        float hn = sigf(op) * tanhf(cn);
        *((t & 1) ? hO : hE) = f2bf(hn);

        // Grid barrier (device scope). Also orders Gt reuse for next step.
        __syncthreads();
        if (tid == 0) {
            __threadfence();
            __hip_atomic_fetch_add(bar, 1u, __ATOMIC_RELEASE, __HIP_MEMORY_SCOPE_AGENT);
            const unsigned target = (unsigned)NBLK * (unsigned)(t + 1);
            long guard = 0;
            while (__hip_atomic_load(bar, __ATOMIC_ACQUIRE, __HIP_MEMORY_SCOPE_AGENT) < target) {
                __builtin_amdgcn_s_sleep(1);
                if (++guard > (1L << 40)) break;   // never in practice; avoids hard hang
            }
        }
        __syncthreads();
    }
}

// ---------------------------------------------------------------------------
// FC head: out[b] = sigmoid(dot(h[b], fc_w) + fc_b)
// ---------------------------------------------------------------------------
__global__ __launch_bounds__(256) void fc_kernel(
    const short* __restrict__ hbuf, const float* __restrict__ fc_w,
    const float* __restrict__ fc_b, float* __restrict__ out)
{
    __shared__ float red[4];
    int b = blockIdx.x;
    int tid = threadIdx.x;
    float s = 0.f;
    for (int k = tid; k < HH; k += 256)
        s += bf2f(hbuf[(size_t)b * HH + k]) * fc_w[k];
    #pragma unroll
    for (int off = 32; off > 0; off >>= 1) s += __shfl_down(s, off);
    if ((tid & 63) == 0) red[tid >> 6] = s;
    __syncthreads();
    if (tid == 0) {
        float tot = red[0] + red[1] + red[2] + red[3] + fc_b[0];
        out[b] = 1.f / (1.f + __expf(-tot));
    }
}

// ---------------------------------------------------------------------------
// Workspace layout (bytes):
//   w_cat @ 0           : 12,582,912
//   bias  @ 12,582,912  :     16,384
//   xbf   @ 12,599,296  : 67,108,864
//   hbuf0 @ 79,708,160  :    524,288
//   hbuf1 @ 80,232,448  :    524,288
//   bar   @ 80,756,736  :         64
// ---------------------------------------------------------------------------
extern "C" void kernel_launch(void* const* d_in, const int* in_sizes, int n_in,
                              void* d_out, int out_size, void* d_ws, size_t ws_size,
                              hipStream_t stream) {
    const int*   text = (const int*)d_in[0];
    const float* emb  = (const float*)d_in[1];
    const float* w_ih = (const float*)d_in[2];
    const float* w_hh = (const float*)d_in[3];
    const float* b_ih = (const float*)d_in[4];
    const float* b_hh = (const float*)d_in[5];
    const float* fc_w = (const float*)d_in[6];
    const float* fc_b = (const float*)d_in[7];
    float* out = (float*)d_out;

    char* ws = (char*)d_ws;
    short*    w_cat = (short*)(ws);
    float*    bias  = (float*)(ws + 12582912);
    short*    xbf   = (short*)(ws + 12599296);
    short*    hbuf0 = (short*)(ws + 79708160);
    short*    hbuf1 = (short*)(ws + 80232448);
    unsigned* bar   = (unsigned*)(ws + 80756736);

    hipMemsetAsync(bar, 0, 64, stream);
    gather_kernel<<<dim3(BB * TT / 4), dim3(256), 0, stream>>>(text, emb, xbf);
    prep_kernel<<<dim3(G4), dim3(256), 0, stream>>>(w_ih, w_hh, b_ih, b_hh, w_cat, bias);

    lstm_persist<<<dim3(NBLK), dim3(1024), 0, stream>>>(
        w_cat, bias, xbf, hbuf0, hbuf1, bar);

    fc_kernel<<<dim3(BB), dim3(256), 0, stream>>>(hbuf0, fc_w, fc_b, out);
}